// Round 1
// 2251.176 us; speedup vs baseline: 1.4224x; 1.4224x over previous
//
#include <hip/hip_runtime.h>

typedef _Float16 half_t;
typedef _Float16 half4 __attribute__((ext_vector_type(4)));
typedef _Float16 half8 __attribute__((ext_vector_type(8)));
typedef float floatx4 __attribute__((ext_vector_type(4)));
typedef unsigned long long ull_t;

#define SEQ 256
#define BATCH 64
#define EMB 256
#define HID 512
#define NOUT 18
#define M_TOT (SEQ*BATCH)   // 16384

// ---------------- ws layout (bytes) ----------------
// flags: 32 slots x 256B (16 per layer)
#define O_FLG    0u          // 8192
#define O_HB0    8192u       // layer0 exchange: 16 regions x 2 parity x 8KB = 262144
#define O_HB1    270336u     // layer1 same
#define O_EMFC16 532480u     // 65536 half = 131072
#define O_WIH0   663552u     // 1024*256 half = 524288
#define O_WIH1   1187840u    // 1024*1024 half = 2097152
#define O_FC16   3284992u    // 18*1024 half = 36864
#define O_PE     3321856u    // post_emb 16384*256 half = 8388608
#define O_XP     11710464u   // xp 16384*1024 half = 33554432 (shared by layer0/layer1)
#define O_OUT    45264896u   // 16384*1024 half (out0 and out1 aliased; stream-ordered safe)
// total 78819328 bytes (< previous 112365824)

// ---------------- init: zero flags + exchange buffers ----------------
__global__ void zero_ws(uint4* p, int n) {
    int i = blockIdx.x * 256 + threadIdx.x;
    if (i < n) p[i] = make_uint4(0u, 0u, 0u, 0u);
}

// ---------------- fp32 -> fp16 convert (8 elems/thread) ----------------
__global__ void cvt_f32f16(const float* __restrict__ s, half_t* __restrict__ d, int n8) {
    int i = blockIdx.x * 256 + threadIdx.x;
    if (i < n8) {
        const float4* s4 = (const float4*)s;
        float4 a = s4[2*i], b = s4[2*i+1];
        half8 h;
        h[0]=(_Float16)a.x; h[1]=(_Float16)a.y; h[2]=(_Float16)a.z; h[3]=(_Float16)a.w;
        h[4]=(_Float16)b.x; h[5]=(_Float16)b.y; h[6]=(_Float16)b.z; h[7]=(_Float16)b.w;
        *(half8*)(d + (size_t)i*8) = h;
    }
}

// ---------------- generic NT GEMM: C[m,n] = sum_k A[m,k]*B[n,k] + bias ----------------
// BM=128 BN=128 BK=32, 256 threads (4 waves 2x2), fp16 MFMA 16x16x32, fp16 out.
template<bool GATHER>
__global__ __launch_bounds__(256)
void gemm_nt(const half_t* __restrict__ A, const float* __restrict__ Atab,
             const int* __restrict__ gidx, const half_t* __restrict__ Bm,
             const float* __restrict__ bias0, const float* __restrict__ bias1,
             half_t* __restrict__ Cout, int M, int N, int K)
{
    __shared__ half8 As8[512];   // 128 x 32 half
    __shared__ half8 Bs8[512];
    half_t* As = (half_t*)As8;
    half_t* Bs = (half_t*)Bs8;

    const int tid  = threadIdx.x;
    const int lane = tid & 63, wid = tid >> 6;
    const int wm = wid >> 1, wn = wid & 1;
    const int ln = lane & 15, hi = lane >> 4;
    const int m0 = blockIdx.x * 128, n0 = blockIdx.y * 128;

    floatx4 acc[4][4] = {};
    const int kTiles = K >> 5;

    for (int kt = 0; kt < kTiles; ++kt) {
        if constexpr (GATHER) {
            int r = tid >> 1, q = tid & 1;
            int row = gidx[m0 + r];
            const float* src = Atab + (size_t)row * EMB + kt*32 + q*16;
            float4 f0 = *(const float4*)(src);
            float4 f1 = *(const float4*)(src + 4);
            float4 f2 = *(const float4*)(src + 8);
            float4 f3 = *(const float4*)(src + 12);
            half8 h0, h1;
            h0[0]=(_Float16)f0.x; h0[1]=(_Float16)f0.y; h0[2]=(_Float16)f0.z; h0[3]=(_Float16)f0.w;
            h0[4]=(_Float16)f1.x; h0[5]=(_Float16)f1.y; h0[6]=(_Float16)f1.z; h0[7]=(_Float16)f1.w;
            h1[0]=(_Float16)f2.x; h1[1]=(_Float16)f2.y; h1[2]=(_Float16)f2.z; h1[3]=(_Float16)f2.w;
            h1[4]=(_Float16)f3.x; h1[5]=(_Float16)f3.y; h1[6]=(_Float16)f3.z; h1[7]=(_Float16)f3.w;
            int c0 = 2*q, c1 = 2*q + 1;
            *(half8*)(As + r*32 + (((c0 + (r>>1)) & 3) * 8)) = h0;
            *(half8*)(As + r*32 + (((c1 + (r>>1)) & 3) * 8)) = h1;
        } else {
            #pragma unroll
            for (int ii = 0; ii < 2; ++ii) {
                int ch = tid + ii*256; int r = ch >> 2, c = ch & 3;
                half8 v = *(const half8*)(A + (size_t)(m0+r)*K + kt*32 + c*8);
                *(half8*)(As + r*32 + (((c + (r>>1)) & 3) * 8)) = v;
            }
        }
        #pragma unroll
        for (int ii = 0; ii < 2; ++ii) {
            int ch = tid + ii*256; int r = ch >> 2, c = ch & 3;
            half8 v = *(const half8*)(Bm + (size_t)(n0+r)*K + kt*32 + c*8);
            *(half8*)(Bs + r*32 + (((c + (r>>1)) & 3) * 8)) = v;
        }
        __syncthreads();

        half8 af[4], bf[4];
        #pragma unroll
        for (int mt = 0; mt < 4; ++mt) {
            int r = wm*64 + mt*16 + ln;
            af[mt] = *(const half8*)(As + r*32 + ((hi + (r>>1)) & 3) * 8);
        }
        #pragma unroll
        for (int nt = 0; nt < 4; ++nt) {
            int r = wn*64 + nt*16 + ln;
            bf[nt] = *(const half8*)(Bs + r*32 + ((hi + (r>>1)) & 3) * 8);
        }
        #pragma unroll
        for (int mt = 0; mt < 4; ++mt)
            #pragma unroll
            for (int nt = 0; nt < 4; ++nt)
                acc[mt][nt] = __builtin_amdgcn_mfma_f32_16x16x32_f16(af[mt], bf[nt], acc[mt][nt], 0, 0, 0);
        __syncthreads();
    }

    #pragma unroll
    for (int mt = 0; mt < 4; ++mt) {
        #pragma unroll
        for (int nt = 0; nt < 4; ++nt) {
            int n = n0 + wn*64 + nt*16 + ln;
            float bv = (bias0 ? bias0[n] : 0.f) + (bias1 ? bias1[n] : 0.f);
            #pragma unroll
            for (int r = 0; r < 4; ++r) {
                int m = m0 + wm*64 + mt*16 + hi*4 + r;
                Cout[(size_t)m*N + n] = (half_t)(acc[mt][nt][r] + bv);
            }
        }
    }
}

// ---------------- persistent bidirectional RNN layer (round 3: pairwise halves) ----------------
// grid = 16 blocks x 256 thr, 1 wave/SIMD (launch_bounds(256,1), ~350 VGPR).
// bid -> dir = bid>>3, batch-group bg = (bid>>1)&3, j-half p = bid&1. Partner = bid^1.
// Block computes j in [p*256, p*256+256) for batches [bg*16, bg*16+16).
// 4 waves x 64 j each; wave holds W rows in afrag (own-half kk remapped to [0,8) so no
// runtime register indexing). Own h-half lives in LDS (double-buffered, rows padded to
// 264 halfs -> <=2-way bank conflict = free). Only the partner's 8KB half crosses L3 per
// step, guarded by a single per-block flag (256B apart, no RMW serialization).
// Per-step order: own-LDS MFMAs first (off critical path) -> poll partner flag ->
// partner loads + MFMAs -> epilogue -> waitcnt -> syncthreads -> post flag.
__global__ __launch_bounds__(256, 1)
void rnn_layer(const half_t* __restrict__ xp, half_t* __restrict__ outbuf,
               const float* __restrict__ whh, ull_t* __restrict__ xch,
               int* __restrict__ flags)
{
    const int bid = blockIdx.x;
    const int dir = bid >> 3;
    const int bg  = (bid >> 1) & 3;
    const int p   = bid & 1;
    const int w   = threadIdx.x >> 6;
    const int lane = threadIdx.x & 63;
    const int ln = lane & 15, hi = lane >> 4;

    __shared__ half_t hlds[2][16][264];   // [dbuf][batch][256 k' + 8 pad]

    // A fragments: afrag[mt][kkL]; kkL<8 = OWN half (global kk = p*8+kkL),
    // kkL>=8 = PARTNER half (global kk = (1-p)*8 + (kkL-8)). All reg indices static.
    half8 afrag[4][16];
    #pragma unroll
    for (int mt = 0; mt < 4; ++mt) {
        #pragma unroll
        for (int kkL = 0; kkL < 16; ++kkL) {
            int kg = ((kkL < 8) ? p : (1 - p)) * 8 + (kkL & 7);
            const float* wp = whh + ((size_t)(dir*HID + p*256 + w*64 + mt*16 + ln))*HID
                                  + kg*32 + hi*8;
            float4 f0 = *(const float4*)wp;
            float4 f1 = *(const float4*)(wp + 4);
            half8 h;
            h[0]=(_Float16)f0.x; h[1]=(_Float16)f0.y; h[2]=(_Float16)f0.z; h[3]=(_Float16)f0.w;
            h[4]=(_Float16)f1.x; h[5]=(_Float16)f1.y; h[6]=(_Float16)f1.z; h[7]=(_Float16)f1.w;
            afrag[mt][kkL] = h;
        }
    }

    // zero own-half LDS buffer 0 (h_0 = 0)
    {
        half_t* z = &hlds[0][0][0];
        for (int i = threadIdx.x; i < 16*264; i += 256) z[i] = (_Float16)0.f;
    }

    const int b = bg*16 + ln;   // this lane's batch column
    const ull_t* pbase = xch + (size_t)((dir*4 + bg)*2 + (1 - p)) * 2048;  // partner writes here
    ull_t*       mbase = xch + (size_t)((dir*4 + bg)*2 + p) * 2048;        // I write here
    int* myfl = flags + bid*64;
    int* pfl  = flags + (bid^1)*64;

    // prefetch xp for step 0; lane's j quads: p*256 + w*64 + mt*16 + hi*4
    half4 xq[4];
    {
        int t0 = dir ? (SEQ-1) : 0;
        const half_t* xb = xp + ((size_t)(t0*BATCH + b))*(2*HID) + dir*HID + p*256 + w*64 + hi*4;
        #pragma unroll
        for (int mt = 0; mt < 4; ++mt) xq[mt] = *(const half4*)(xb + mt*16);
    }

    __syncthreads();

    int cb = 0;
    for (int step = 0; step < SEQ; ++step) {
        const int t = dir ? (SEQ-1 - step) : step;

        floatx4 acc[4] = {};

        // ---- own half from LDS: compute before waiting on partner ----
        #pragma unroll
        for (int kk8 = 0; kk8 < 8; ++kk8) {
            half8 bo = *(const half8*)&hlds[cb][ln][kk8*32 + hi*8];
            #pragma unroll
            for (int mt = 0; mt < 4; ++mt)
                acc[mt] = __builtin_amdgcn_mfma_f32_16x16x32_f16(afrag[mt][kk8], bo, acc[mt], 0, 0, 0);
        }

        // ---- wait for partner's h_step, then load its 8KB half ----
        if (step) {
            if (lane == 0)
                while (__hip_atomic_load(pfl, __ATOMIC_RELAXED, __HIP_MEMORY_SCOPE_AGENT) < step)
                    __builtin_amdgcn_s_sleep(1);
        }
        const ull_t* ps = pbase + (size_t)(step & 1)*1024 + ln*64 + hi*2;
        ull_t ua[8], uc[8];
        #pragma unroll
        for (int kk8 = 0; kk8 < 8; ++kk8) {
            ua[kk8] = __hip_atomic_load(ps + kk8*8,     __ATOMIC_RELAXED, __HIP_MEMORY_SCOPE_AGENT);
            uc[kk8] = __hip_atomic_load(ps + kk8*8 + 1, __ATOMIC_RELAXED, __HIP_MEMORY_SCOPE_AGENT);
        }
        #pragma unroll
        for (int kk8 = 0; kk8 < 8; ++kk8) {
            struct U2 { ull_t a, c; } u; u.a = ua[kk8]; u.c = uc[kk8];
            half8 bp = __builtin_bit_cast(half8, u);
            #pragma unroll
            for (int mt = 0; mt < 4; ++mt)
                acc[mt] = __builtin_amdgcn_mfma_f32_16x16x32_f16(afrag[mt][8 + kk8], bp, acc[mt], 0, 0, 0);
        }

        // ---- epilogue: v = relu(acc + xp); lane holds j quad per mt for batch b ----
        const size_t orow = ((size_t)t*BATCH + b)*(2*HID) + dir*HID + p*256 + w*64 + hi*4;
        const int nb = cb ^ 1;
        ull_t* md = mbase + (size_t)((step+1) & 1)*1024 + ln*64 + w*16 + hi;
        #pragma unroll
        for (int mt = 0; mt < 4; ++mt) {
            half4 hv;
            #pragma unroll
            for (int r = 0; r < 4; ++r)
                hv[r] = (_Float16)fmaxf(acc[mt][r] + (float)xq[mt][r], 0.f);
            *(half4*)(outbuf + orow + mt*16) = hv;               // normal cached store
            if (step + 1 < SEQ) {
                *(half4*)&hlds[nb][ln][w*64 + mt*16 + hi*4] = hv;
                __hip_atomic_store(md + mt*4, __builtin_bit_cast(ull_t, hv),
                                   __ATOMIC_RELAXED, __HIP_MEMORY_SCOPE_AGENT);
            }
        }

        if (step + 1 < SEQ) {
            __builtin_amdgcn_s_waitcnt(0);    // exchange stores acked at coherence point
            __syncthreads();                  // all 4 waves done (LDS + global publish)
            if (threadIdx.x == 0)
                __hip_atomic_store(myfl, step + 1, __ATOMIC_RELAXED, __HIP_MEMORY_SCOPE_AGENT);
            // prefetch xp for next step (off critical path)
            int tn = dir ? (SEQ-2 - step) : (step+1);
            const half_t* xb = xp + ((size_t)(tn*BATCH + b))*(2*HID) + dir*HID + p*256 + w*64 + hi*4;
            #pragma unroll
            for (int mt = 0; mt < 4; ++mt) xq[mt] = *(const half4*)(xb + mt*16);
            cb = nb;
        }
    }
}

// ---------------- final FC: [16384,1024] x [18,1024]^T + b ----------------
__global__ __launch_bounds__(256)
void fc_kernel(const half_t* __restrict__ X, const half_t* __restrict__ W16,
               const float* __restrict__ bias, float* __restrict__ Y)
{
    __shared__ half8 Ws8[2304];   // 18*1024 half
    half_t* Ws = (half_t*)Ws8;
    for (int ch = threadIdx.x; ch < 2304; ch += 256)
        Ws8[ch] = *(const half8*)(W16 + (size_t)ch*8);
    __syncthreads();

    int wi = threadIdx.x >> 6, lane = threadIdx.x & 63;
    int m = blockIdx.x*4 + wi;
    const half_t* xr = X + (size_t)m*1024 + lane*16;
    half8 x0 = *(const half8*)xr;
    half8 x1 = *(const half8*)(xr + 8);
    float xa[16];
    #pragma unroll
    for (int i = 0; i < 8; ++i) { xa[i] = (float)x0[i]; xa[8+i] = (float)x1[i]; }

    for (int n = 0; n < NOUT; ++n) {
        const half_t* wr = Ws + n*1024 + lane*16;
        half8 w0 = *(const half8*)wr;
        half8 w1 = *(const half8*)(wr + 8);
        float s = 0.f;
        #pragma unroll
        for (int i = 0; i < 8; ++i) s += xa[i]*(float)w0[i] + xa[8+i]*(float)w1[i];
        #pragma unroll
        for (int off = 32; off > 0; off >>= 1) s += __shfl_down(s, off, 64);
        if (lane == 0) Y[(size_t)m*NOUT + n] = s + bias[n];
    }
}

// ---------------- launcher ----------------
extern "C" void kernel_launch(void* const* d_in, const int* in_sizes, int n_in,
                              void* d_out, int out_size, void* d_ws, size_t ws_size,
                              hipStream_t stream)
{
    const int*   text    = (const int*)  d_in[0];
    const float* emb     = (const float*)d_in[1];
    const float* emfc_w  = (const float*)d_in[2];
    const float* emfc_b  = (const float*)d_in[3];
    const float* w_ih0   = (const float*)d_in[4];
    const float* w_hh0   = (const float*)d_in[5];
    const float* b_ih0   = (const float*)d_in[6];
    const float* b_hh0   = (const float*)d_in[7];
    const float* w_ih1   = (const float*)d_in[8];
    const float* w_hh1   = (const float*)d_in[9];
    const float* b_ih1   = (const float*)d_in[10];
    const float* b_hh1   = (const float*)d_in[11];
    const float* fc_w    = (const float*)d_in[12];
    const float* fc_b    = (const float*)d_in[13];
    float* out = (float*)d_out;

    char* ws = (char*)d_ws;
    int*    flg    = (int*)   (ws + O_FLG);
    ull_t*  hb0    = (ull_t*) (ws + O_HB0);
    ull_t*  hb1    = (ull_t*) (ws + O_HB1);
    half_t* emfc16 = (half_t*)(ws + O_EMFC16);
    half_t* wih0   = (half_t*)(ws + O_WIH0);
    half_t* wih1   = (half_t*)(ws + O_WIH1);
    half_t* fc16   = (half_t*)(ws + O_FC16);
    half_t* pe     = (half_t*)(ws + O_PE);
    half_t* xp     = (half_t*)(ws + O_XP);
    half_t* out0   = (half_t*)(ws + O_OUT);
    half_t* out1   = (half_t*)(ws + O_OUT);   // aliased: out0 dead once xp1 GEMM done

    // 1) zero flags + exchange buffers  (532480 bytes = 33280 uint4)
    zero_ws<<<130, 256, 0, stream>>>((uint4*)ws, 33280);

    // 2) weight conversions fp32->fp16
    cvt_f32f16<<<32,  256, 0, stream>>>(emfc_w, emfc16, 8192);
    cvt_f32f16<<<128, 256, 0, stream>>>(w_ih0,  wih0,  32768);
    cvt_f32f16<<<512, 256, 0, stream>>>(w_ih1,  wih1, 131072);
    cvt_f32f16<<<9,   256, 0, stream>>>(fc_w,   fc16,   2304);

    // 3) post_emb = gather(emb, text) @ emfc_w^T + emfc_b
    gemm_nt<true><<<dim3(M_TOT/128, EMB/128), 256, 0, stream>>>(
        nullptr, emb, text, emfc16, emfc_b, nullptr, pe, M_TOT, EMB, EMB);

    // 4) xp0 = post_emb @ w_ih0^T + (b_ih0 + b_hh0)
    gemm_nt<false><<<dim3(M_TOT/128, (2*HID)/128), 256, 0, stream>>>(
        pe, nullptr, nullptr, wih0, b_ih0, b_hh0, xp, M_TOT, 2*HID, EMB);

    // 5) layer0 recurrence (both directions, pairwise j-halves)
    rnn_layer<<<16, 256, 0, stream>>>(xp, out0, w_hh0, hb0, flg);

    // 6) xp1 = out0 @ w_ih1^T + (b_ih1 + b_hh1)
    gemm_nt<false><<<dim3(M_TOT/128, (2*HID)/128), 256, 0, stream>>>(
        out0, nullptr, nullptr, wih1, b_ih1, b_hh1, xp, M_TOT, 2*HID, 2*HID);

    // 7) layer1 recurrence
    rnn_layer<<<16, 256, 0, stream>>>(xp, out1, w_hh1, hb1, flg + 1024);

    // 8) out = out1 @ fc_w^T + fc_b
    fc_kernel<<<M_TOT/4, 256, 0, stream>>>(out1, fc16, fc_b, out);
}

// Round 2
// 1851.465 us; speedup vs baseline: 1.7295x; 1.2159x over previous
//
#include <hip/hip_runtime.h>

typedef _Float16 half_t;
typedef _Float16 half4 __attribute__((ext_vector_type(4)));
typedef _Float16 half8 __attribute__((ext_vector_type(8)));
typedef float floatx4 __attribute__((ext_vector_type(4)));
typedef unsigned long long ull_t;

#define SEQ 256
#define BATCH 64
#define EMB 256
#define HID 512
#define NOUT 18
#define M_TOT (SEQ*BATCH)   // 16384

// rnn_layer geometry
#define KK_REG 13            // K-tiles (of 32) held in registers: k < 416
#define K_REG  (KK_REG*32)   // 416
#define KTAIL  (HID - K_REG) // 96 cols in LDS
#define WROW   104           // LDS W row stride in halfs (96 + 8 pad -> 2-way banks)
#define HROW   520           // LDS h row stride in halfs (512 + 8 pad -> 2-way banks)
#define WLDS_BYTES (HID*WROW*2)          // 106496
#define HLDS_BYTES (2*16*HROW*2)         // 33280
#define LDS_BYTES  (WLDS_BYTES + HLDS_BYTES)  // 139776

// ---------------- ws layout (bytes) ----------------
#define O_WHH0_16 0u          // 2*512*512 half = 1048576
#define O_WHH1_16 1048576u    // 1048576
#define O_EMFC16  2097152u    // 65536 half = 131072
#define O_WIH0    2228224u    // 1024*256 half = 524288
#define O_WIH1    2752512u    // 1024*1024 half = 2097152
#define O_FC16    4849664u    // 18*1024 half = 36864
#define O_PE      4886528u    // post_emb 16384*256 half = 8388608
#define O_XP      13275136u   // xp 16384*1024 half = 33554432 (shared by layer0/layer1)
#define O_OUT     46829568u   // 16384*1024 half (out0/out1 aliased; stream-ordered safe)
// total 80384000 bytes

// ---------------- fp32 -> fp16 convert (8 elems/thread) ----------------
__global__ void cvt_f32f16(const float* __restrict__ s, half_t* __restrict__ d, int n8) {
    int i = blockIdx.x * 256 + threadIdx.x;
    if (i < n8) {
        const float4* s4 = (const float4*)s;
        float4 a = s4[2*i], b = s4[2*i+1];
        half8 h;
        h[0]=(_Float16)a.x; h[1]=(_Float16)a.y; h[2]=(_Float16)a.z; h[3]=(_Float16)a.w;
        h[4]=(_Float16)b.x; h[5]=(_Float16)b.y; h[6]=(_Float16)b.z; h[7]=(_Float16)b.w;
        *(half8*)(d + (size_t)i*8) = h;
    }
}

// ---------------- generic NT GEMM: C[m,n] = sum_k A[m,k]*B[n,k] + bias ----------------
// BM=128 BN=128 BK=32, 256 threads (4 waves 2x2), fp16 MFMA 16x16x32, fp16 out.
template<bool GATHER>
__global__ __launch_bounds__(256)
void gemm_nt(const half_t* __restrict__ A, const float* __restrict__ Atab,
             const int* __restrict__ gidx, const half_t* __restrict__ Bm,
             const float* __restrict__ bias0, const float* __restrict__ bias1,
             half_t* __restrict__ Cout, int M, int N, int K)
{
    __shared__ half8 As8[512];   // 128 x 32 half
    __shared__ half8 Bs8[512];
    half_t* As = (half_t*)As8;
    half_t* Bs = (half_t*)Bs8;

    const int tid  = threadIdx.x;
    const int lane = tid & 63, wid = tid >> 6;
    const int wm = wid >> 1, wn = wid & 1;
    const int ln = lane & 15, hi = lane >> 4;
    const int m0 = blockIdx.x * 128, n0 = blockIdx.y * 128;

    floatx4 acc[4][4] = {};
    const int kTiles = K >> 5;

    for (int kt = 0; kt < kTiles; ++kt) {
        if constexpr (GATHER) {
            int r = tid >> 1, q = tid & 1;
            int row = gidx[m0 + r];
            const float* src = Atab + (size_t)row * EMB + kt*32 + q*16;
            float4 f0 = *(const float4*)(src);
            float4 f1 = *(const float4*)(src + 4);
            float4 f2 = *(const float4*)(src + 8);
            float4 f3 = *(const float4*)(src + 12);
            half8 h0, h1;
            h0[0]=(_Float16)f0.x; h0[1]=(_Float16)f0.y; h0[2]=(_Float16)f0.z; h0[3]=(_Float16)f0.w;
            h0[4]=(_Float16)f1.x; h0[5]=(_Float16)f1.y; h0[6]=(_Float16)f1.z; h0[7]=(_Float16)f1.w;
            h1[0]=(_Float16)f2.x; h1[1]=(_Float16)f2.y; h1[2]=(_Float16)f2.z; h1[3]=(_Float16)f2.w;
            h1[4]=(_Float16)f3.x; h1[5]=(_Float16)f3.y; h1[6]=(_Float16)f3.z; h1[7]=(_Float16)f3.w;
            int c0 = 2*q, c1 = 2*q + 1;
            *(half8*)(As + r*32 + (((c0 + (r>>1)) & 3) * 8)) = h0;
            *(half8*)(As + r*32 + (((c1 + (r>>1)) & 3) * 8)) = h1;
        } else {
            #pragma unroll
            for (int ii = 0; ii < 2; ++ii) {
                int ch = tid + ii*256; int r = ch >> 2, c = ch & 3;
                half8 v = *(const half8*)(A + (size_t)(m0+r)*K + kt*32 + c*8);
                *(half8*)(As + r*32 + (((c + (r>>1)) & 3) * 8)) = v;
            }
        }
        #pragma unroll
        for (int ii = 0; ii < 2; ++ii) {
            int ch = tid + ii*256; int r = ch >> 2, c = ch & 3;
            half8 v = *(const half8*)(Bm + (size_t)(n0+r)*K + kt*32 + c*8);
            *(half8*)(Bs + r*32 + (((c + (r>>1)) & 3) * 8)) = v;
        }
        __syncthreads();

        half8 af[4], bf[4];
        #pragma unroll
        for (int mt = 0; mt < 4; ++mt) {
            int r = wm*64 + mt*16 + ln;
            af[mt] = *(const half8*)(As + r*32 + ((hi + (r>>1)) & 3) * 8);
        }
        #pragma unroll
        for (int nt = 0; nt < 4; ++nt) {
            int r = wn*64 + nt*16 + ln;
            bf[nt] = *(const half8*)(Bs + r*32 + ((hi + (r>>1)) & 3) * 8);
        }
        #pragma unroll
        for (int mt = 0; mt < 4; ++mt)
            #pragma unroll
            for (int nt = 0; nt < 4; ++nt)
                acc[mt][nt] = __builtin_amdgcn_mfma_f32_16x16x32_f16(af[mt], bf[nt], acc[mt][nt], 0, 0, 0);
        __syncthreads();
    }

    #pragma unroll
    for (int mt = 0; mt < 4; ++mt) {
        #pragma unroll
        for (int nt = 0; nt < 4; ++nt) {
            int n = n0 + wn*64 + nt*16 + ln;
            float bv = (bias0 ? bias0[n] : 0.f) + (bias1 ? bias1[n] : 0.f);
            #pragma unroll
            for (int r = 0; r < 4; ++r) {
                int m = m0 + wm*64 + mt*16 + hi*4 + r;
                Cout[(size_t)m*N + n] = (half_t)(acc[mt][nt][r] + bv);
            }
        }
    }
}

// ---------------- persistent bidirectional RNN layer (round 4: block-local, no sync) ----------------
// grid = 8 blocks (2 dir x 4 batch-groups) x 256 thr, 1 wave/SIMD.
// Each block owns ALL 512 j for its 16 batches -> NO inter-block communication.
// W residency: k<416 in unified VGPR+AGPR regs (afrag[8][13] = 416 regs/thread; proven
// feasible by round-1's 256-VGPR + AGPR allocation at launch_bounds(256,1));
// k in [416,512) in LDS (512 x 104-padded halfs). h double-buffered in LDS (rows padded
// to 520 halfs -> 2-way bank aliasing = free). One __syncthreads per step.
__global__ __launch_bounds__(256, 1)
void rnn_layer(const half_t* __restrict__ xp, half_t* __restrict__ outbuf,
               const half_t* __restrict__ whh16)
{
    extern __shared__ char smem[];
    half_t* wlds = (half_t*)smem;                  // [512][WROW]
    half_t* hlds = (half_t*)(smem + WLDS_BYTES);   // [2][16][HROW]

    const int bid = blockIdx.x;
    const int dir = bid >> 2;
    const int bg  = bid & 3;
    const int wid = threadIdx.x >> 6;
    const int lane = threadIdx.x & 63;
    const int ln = lane & 15, hi = lane >> 4;

    const half_t* wbase = whh16 + (size_t)dir * HID * HID;

    // A fragments in regs: wave wid owns j rows [wid*128, wid*128+128), k < 416.
    half8 afrag[8][KK_REG];
    #pragma unroll
    for (int mt = 0; mt < 8; ++mt) {
        #pragma unroll
        for (int kk = 0; kk < KK_REG; ++kk)
            afrag[mt][kk] = *(const half8*)(wbase + (size_t)(wid*128 + mt*16 + ln)*HID + kk*32 + hi*8);
    }

    // stage W k-tail [416,512) into LDS: 512 rows x 12 half8
    for (int idx = threadIdx.x; idx < HID*12; idx += 256) {
        int row = idx / 12, c8 = idx % 12;
        *(half8*)(wlds + row*WROW + c8*8) =
            *(const half8*)(wbase + (size_t)row*HID + K_REG + c8*8);
    }
    // zero both h buffers (h_0 = 0)
    for (int i = threadIdx.x; i < HLDS_BYTES/16; i += 256)
        ((uint4*)hlds)[i] = make_uint4(0u,0u,0u,0u);

    const int b = bg*16 + ln;        // this lane's batch column
    const int jq = wid*128 + hi*4;   // j quad base; mt adds 16

    // prefetch xp for step 0
    half4 xq[8];
    {
        int t0 = dir ? (SEQ-1) : 0;
        const half_t* xb = xp + ((size_t)(t0*BATCH + b))*(2*HID) + dir*HID + jq;
        #pragma unroll
        for (int mt = 0; mt < 8; ++mt) xq[mt] = *(const half4*)(xb + mt*16);
    }

    __syncthreads();

    int cb = 0;
    for (int step = 0; step < SEQ; ++step) {
        const int t = dir ? (SEQ-1 - step) : step;
        const half_t* hrow = hlds + (size_t)(cb*16 + ln)*HROW;

        floatx4 acc[8] = {};

        // k < 416: W from registers, h from LDS
        #pragma unroll
        for (int kk = 0; kk < KK_REG; ++kk) {
            half8 bf = *(const half8*)(hrow + kk*32 + hi*8);
            #pragma unroll
            for (int mt = 0; mt < 8; ++mt)
                acc[mt] = __builtin_amdgcn_mfma_f32_16x16x32_f16(afrag[mt][kk], bf, acc[mt], 0, 0, 0);
        }
        // k in [416,512): both W and h from LDS
        #pragma unroll
        for (int kt = 0; kt < 3; ++kt) {
            half8 bf = *(const half8*)(hrow + (KK_REG+kt)*32 + hi*8);
            #pragma unroll
            for (int mt = 0; mt < 8; ++mt) {
                half8 wf = *(const half8*)(wlds + (wid*128 + mt*16 + ln)*WROW + kt*32 + hi*8);
                acc[mt] = __builtin_amdgcn_mfma_f32_16x16x32_f16(wf, bf, acc[mt], 0, 0, 0);
            }
        }

        // epilogue: v = relu(acc + xp); lane holds j quad per mt for batch b
        const size_t orow = ((size_t)t*BATCH + b)*(2*HID) + dir*HID + jq;
        const int nb = cb ^ 1;
        half_t* hw = hlds + (size_t)(nb*16 + ln)*HROW + jq;
        #pragma unroll
        for (int mt = 0; mt < 8; ++mt) {
            half4 hv;
            #pragma unroll
            for (int r = 0; r < 4; ++r)
                hv[r] = (_Float16)fmaxf(acc[mt][r] + (float)xq[mt][r], 0.f);
            *(half4*)(outbuf + orow + mt*16) = hv;
            if (step + 1 < SEQ) *(half4*)(hw + mt*16) = hv;
        }

        if (step + 1 < SEQ) {
            __syncthreads();     // h(t+1) fully written before anyone reads it
            // prefetch xp for next step (off critical path)
            int tn = dir ? (SEQ-2 - step) : (step+1);
            const half_t* xb = xp + ((size_t)(tn*BATCH + b))*(2*HID) + dir*HID + jq;
            #pragma unroll
            for (int mt = 0; mt < 8; ++mt) xq[mt] = *(const half4*)(xb + mt*16);
            cb = nb;
        }
    }
}

// ---------------- final FC: [16384,1024] x [18,1024]^T + b ----------------
__global__ __launch_bounds__(256)
void fc_kernel(const half_t* __restrict__ X, const half_t* __restrict__ W16,
               const float* __restrict__ bias, float* __restrict__ Y)
{
    __shared__ half8 Ws8[2304];   // 18*1024 half
    half_t* Ws = (half_t*)Ws8;
    for (int ch = threadIdx.x; ch < 2304; ch += 256)
        Ws8[ch] = *(const half8*)(W16 + (size_t)ch*8);
    __syncthreads();

    int wi = threadIdx.x >> 6, lane = threadIdx.x & 63;
    int m = blockIdx.x*4 + wi;
    const half_t* xr = X + (size_t)m*1024 + lane*16;
    half8 x0 = *(const half8*)xr;
    half8 x1 = *(const half8*)(xr + 8);
    float xa[16];
    #pragma unroll
    for (int i = 0; i < 8; ++i) { xa[i] = (float)x0[i]; xa[8+i] = (float)x1[i]; }

    for (int n = 0; n < NOUT; ++n) {
        const half_t* wr = Ws + n*1024 + lane*16;
        half8 w0 = *(const half8*)wr;
        half8 w1 = *(const half8*)(wr + 8);
        float s = 0.f;
        #pragma unroll
        for (int i = 0; i < 8; ++i) s += xa[i]*(float)w0[i] + xa[8+i]*(float)w1[i];
        #pragma unroll
        for (int off = 32; off > 0; off >>= 1) s += __shfl_down(s, off, 64);
        if (lane == 0) Y[(size_t)m*NOUT + n] = s + bias[n];
    }
}

// ---------------- launcher ----------------
extern "C" void kernel_launch(void* const* d_in, const int* in_sizes, int n_in,
                              void* d_out, int out_size, void* d_ws, size_t ws_size,
                              hipStream_t stream)
{
    const int*   text    = (const int*)  d_in[0];
    const float* emb     = (const float*)d_in[1];
    const float* emfc_w  = (const float*)d_in[2];
    const float* emfc_b  = (const float*)d_in[3];
    const float* w_ih0   = (const float*)d_in[4];
    const float* w_hh0   = (const float*)d_in[5];
    const float* b_ih0   = (const float*)d_in[6];
    const float* b_hh0   = (const float*)d_in[7];
    const float* w_ih1   = (const float*)d_in[8];
    const float* w_hh1   = (const float*)d_in[9];
    const float* b_ih1   = (const float*)d_in[10];
    const float* b_hh1   = (const float*)d_in[11];
    const float* fc_w    = (const float*)d_in[12];
    const float* fc_b    = (const float*)d_in[13];
    float* out = (float*)d_out;

    char* ws = (char*)d_ws;
    half_t* whh0_16 = (half_t*)(ws + O_WHH0_16);
    half_t* whh1_16 = (half_t*)(ws + O_WHH1_16);
    half_t* emfc16  = (half_t*)(ws + O_EMFC16);
    half_t* wih0    = (half_t*)(ws + O_WIH0);
    half_t* wih1    = (half_t*)(ws + O_WIH1);
    half_t* fc16    = (half_t*)(ws + O_FC16);
    half_t* pe      = (half_t*)(ws + O_PE);
    half_t* xp      = (half_t*)(ws + O_XP);
    half_t* out0    = (half_t*)(ws + O_OUT);
    half_t* out1    = (half_t*)(ws + O_OUT);   // aliased: out0 dead once xp1 GEMM done

    // one-time: allow 136KB dynamic LDS for rnn_layer (host-side attr; capture-safe)
    static int attr_done = 0;
    if (!attr_done) {
        hipFuncSetAttribute((const void*)rnn_layer,
                            hipFuncAttributeMaxDynamicSharedMemorySize, LDS_BYTES);
        attr_done = 1;
    }

    // 1) weight conversions fp32->fp16
    cvt_f32f16<<<32,  256, 0, stream>>>(emfc_w, emfc16, 8192);
    cvt_f32f16<<<128, 256, 0, stream>>>(w_ih0,  wih0,  32768);
    cvt_f32f16<<<512, 256, 0, stream>>>(w_ih1,  wih1, 131072);
    cvt_f32f16<<<256, 256, 0, stream>>>(w_hh0,  whh0_16, 65536);
    cvt_f32f16<<<256, 256, 0, stream>>>(w_hh1,  whh1_16, 65536);
    cvt_f32f16<<<9,   256, 0, stream>>>(fc_w,   fc16,   2304);

    // 2) post_emb = gather(emb, text) @ emfc_w^T + emfc_b
    gemm_nt<true><<<dim3(M_TOT/128, EMB/128), 256, 0, stream>>>(
        nullptr, emb, text, emfc16, emfc_b, nullptr, pe, M_TOT, EMB, EMB);

    // 3) xp0 = post_emb @ w_ih0^T + (b_ih0 + b_hh0)
    gemm_nt<false><<<dim3(M_TOT/128, (2*HID)/128), 256, 0, stream>>>(
        pe, nullptr, nullptr, wih0, b_ih0, b_hh0, xp, M_TOT, 2*HID, EMB);

    // 4) layer0 recurrence (8 independent blocks, no inter-block sync)
    rnn_layer<<<8, 256, LDS_BYTES, stream>>>(xp, out0, whh0_16);

    // 5) xp1 = out0 @ w_ih1^T + (b_ih1 + b_hh1)
    gemm_nt<false><<<dim3(M_TOT/128, (2*HID)/128), 256, 0, stream>>>(
        out0, nullptr, nullptr, wih1, b_ih1, b_hh1, xp, M_TOT, 2*HID, 2*HID);

    // 6) layer1 recurrence
    rnn_layer<<<8, 256, LDS_BYTES, stream>>>(xp, out1, whh1_16);

    // 7) out = out1 @ fc_w^T + fc_b
    fc_kernel<<<M_TOT/4, 256, 0, stream>>>(out1, fc16, fc_b, out);
}